// Round 7
// baseline (255.405 us; speedup 1.0000x reference)
//
#include <hip/hip_runtime.h>
#include <math.h>

#define LN 8      // layers
#define NRBF 256
#define FD 16
#define OUTD 3
#define KC (-0.72134752044f)   // -0.5 * log2(e)

typedef __attribute__((ext_vector_type(8))) short short8;   // 8 x bf16
typedef __attribute__((ext_vector_type(4))) float floatx4;

__device__ __forceinline__ short f2bf(float f) {
    unsigned u = __builtin_bit_cast(unsigned, f);
    u += 0x7fffu + ((u >> 16) & 1u);          // RNE
    return (short)(u >> 16);
}

// Workspace:
//   PKB: short8[(nt*8+j)*64 + lane]  (128 KB)  B-fragments, lane-ordered:
//        n = nt*16+(lane&15), k = (lane>>4)*8+e, m=k>>1 -> {A, -2*A*C}
//   EPI: float4[nt*128 + j*16 + l]   (32 KB)   {KC*t3prefix, w0, w1, w2}, n=nt*16+l

__global__ __launch_bounds__(256) void prep(
    const float* __restrict__ centers, const float* __restrict__ betas,
    const float* __restrict__ W, short* __restrict__ PKB, float* __restrict__ EPI)
{
    __shared__ float ls[LN * 32];
    int blk = blockIdx.x;
    int tid = threadIdx.x;
    if (blk < 32) {
        // ---- PKB: one thread per (j, nt, lane) ----
        int t = blk * 256 + tid;           // 8192 total
        int lane = t & 63;
        int nt   = (t >> 6) & 15;
        int j    = t >> 10;
        int n    = nt * 16 + (lane & 15);
        int kq   = lane >> 4;
        size_t base = ((size_t)(j * NRBF + n)) * FD + kq * 4;
        float4 bq = *(const float4*)(betas + base);
        float4 cq = *(const float4*)(centers + base);
        float a0 = __expf(bq.x), a1 = __expf(bq.y), a2 = __expf(bq.z), a3 = __expf(bq.w);
        short8 v;
        v[0] = f2bf(a0); v[1] = f2bf(-2.0f * a0 * cq.x);
        v[2] = f2bf(a1); v[3] = f2bf(-2.0f * a1 * cq.y);
        v[4] = f2bf(a2); v[5] = f2bf(-2.0f * a2 * cq.z);
        v[6] = f2bf(a3); v[7] = f2bf(-2.0f * a3 * cq.w);
        *((short8*)(PKB + (size_t)((nt * 8 + j) * 64 + lane) * 8)) = v;
    } else {
        // ---- EPI: block handles a 32-wide n slice, all 8 layers ----
        int jj = tid >> 5;                  // 0..7
        int nl = tid & 31;
        int n  = (blk - 32) * 32 + nl;
        const float* bp = betas   + ((size_t)(jj * NRBF + n)) * FD;
        const float* cp = centers + ((size_t)(jj * NRBF + n)) * FD;
        float s = 0.f;
#pragma unroll
        for (int q = 0; q < 4; ++q) {
            float4 bq = *(const float4*)(bp + q * 4);
            float4 cq = *(const float4*)(cp + q * 4);
            s = fmaf(__expf(bq.x) * cq.x, cq.x, s);
            s = fmaf(__expf(bq.y) * cq.y, cq.y, s);
            s = fmaf(__expf(bq.z) * cq.z, cq.z, s);
            s = fmaf(__expf(bq.w) * cq.w, cq.w, s);
        }
        ls[jj * 32 + nl] = s;
        __syncthreads();
        float t3 = 0.f;
        for (int j2 = 0; j2 <= jj; ++j2) t3 += ls[j2 * 32 + nl];
        float4 e;
        e.x = KC * t3;
        e.y = W[0 * (LN * NRBF) + jj * NRBF + n];
        e.z = W[1 * (LN * NRBF) + jj * NRBF + n];
        e.w = W[2 * (LN * NRBF) + jj * NRBF + n];
        int nt = n >> 4, l = n & 15;
        ((float4*)EPI)[nt * 128 + jj * 16 + l] = e;
    }
}

// One BLOCK = one 16-sample tile; 4 waves, wave w handles nt = w*4..w*4+3.
// Single acc chain, minimal registers, launch_bounds(256,8) targets <=64 regs
// so 8 waves/SIMD can be resident. Cross-wave reduce via 768 B LDS.
__global__ __launch_bounds__(256, 8) void rbf_mfma(
    const float* __restrict__ feats, const short* __restrict__ PKB,
    const float* __restrict__ EPI, const float* __restrict__ bias,
    float* __restrict__ out, int B)
{
    __shared__ float red[4][48];

    int tid  = threadIdx.x;
    int lane = tid & 63;
    int w    = __builtin_amdgcn_readfirstlane(tid >> 6);   // wave-uniform -> SGPR
    int b0   = blockIdx.x * 16;
    int m    = lane & 15;
    int kq   = lane >> 4;

    // A-fragments: lane holds sample b0+m, k-range kq*8.. of each layer
    int brow = b0 + m; if (brow >= B) brow = B - 1;
    const float* xrow = feats + (size_t)brow * (LN * FD) + kq * 4;
    short8 afrag[LN];
#pragma unroll
    for (int j = 0; j < LN; ++j) {
        float4 x = *((const float4*)(xrow + j * FD));
        short8 f;
        f[0] = f2bf(x.x * x.x); f[1] = f2bf(x.x);
        f[2] = f2bf(x.y * x.y); f[3] = f2bf(x.y);
        f[4] = f2bf(x.z * x.z); f[5] = f2bf(x.z);
        f[6] = f2bf(x.w * x.w); f[7] = f2bf(x.w);
        afrag[j] = f;
    }

    float oacc[12];
#pragma unroll
    for (int i = 0; i < 12; ++i) oacc[i] = 0.f;

#pragma unroll 1
    for (int g = 0; g < 4; ++g) {
        int nt = w * 4 + g;                 // wave-uniform (SGPR)
        // uniform bases in SGPRs; lane part added once
        const short8* pb = (const short8*)PKB + (size_t)(nt * 8) * 64 + lane;  // j-stride 64 (1 KB)
        const float4* ep = (const float4*)EPI + (size_t)nt * 128 + m;          // j-stride 16 (256 B)
        floatx4 acc = {0.f, 0.f, 0.f, 0.f};
#pragma unroll
        for (int j = 0; j < LN; ++j) {
            short8 bfrag = pb[j * 64];
            float4 e     = ep[j * 16];
            acc = __builtin_amdgcn_mfma_f32_16x16x32_bf16(afrag[j], bfrag, acc, 0, 0, 0);
#pragma unroll
            for (int r = 0; r < 4; ++r) {
                float rv = __builtin_amdgcn_exp2f(fmaf(acc[r], KC, e.x));
                oacc[r * 3 + 0] = fmaf(rv, e.y, oacc[r * 3 + 0]);
                oacc[r * 3 + 1] = fmaf(rv, e.z, oacc[r * 3 + 1]);
                oacc[r * 3 + 2] = fmaf(rv, e.w, oacc[r * 3 + 2]);
            }
        }
    }

    // intra-wave reduce over the 16 n-lanes (xor 1,2,4,8 stay within kq group)
#pragma unroll
    for (int i = 0; i < 12; ++i) {
        oacc[i] += __shfl_xor(oacc[i], 1);
        oacc[i] += __shfl_xor(oacc[i], 2);
        oacc[i] += __shfl_xor(oacc[i], 4);
        oacc[i] += __shfl_xor(oacc[i], 8);
    }

    if (m < OUTD) {
#pragma unroll
        for (int r = 0; r < 4; ++r)
            red[w][kq * 12 + r * 3 + m] = oacc[r * 3 + m];
    }
    __syncthreads();

    if (tid < 48) {
        int o = tid % 3;
        int idx = b0 * 3 + tid;
        if (idx < B * 3) {
            float s = red[0][tid] + red[1][tid] + red[2][tid] + red[3][tid] + bias[o];
            out[idx] = s;                    // contiguous 192 B per block
        }
    }
}

extern "C" void kernel_launch(void* const* d_in, const int* in_sizes, int n_in,
                              void* d_out, int out_size, void* d_ws, size_t ws_size,
                              hipStream_t stream) {
    // inputs: 0=x (UNUSED by reference), 1=feats, 2=centers, 3=betas, 4=W, 5=b
    const float* feats   = (const float*)d_in[1];
    const float* centers = (const float*)d_in[2];
    const float* betas   = (const float*)d_in[3];
    const float* W       = (const float*)d_in[4];
    const float* bias    = (const float*)d_in[5];
    float* out = (float*)d_out;
    int B = in_sizes[1] / (LN * FD);

    short* PKB = (short*)d_ws;                       // 65536 shorts = 128 KB
    float* EPI = (float*)((char*)d_ws + 65536 * 2);  // 8192 floats = 32 KB

    prep<<<40, 256, 0, stream>>>(centers, betas, W, PKB, EPI);

    int tiles = (B + 15) / 16;
    rbf_mfma<<<tiles, 256, 0, stream>>>(feats, PKB, EPI, bias, out, B);
}

// Round 8
// 164.115 us; speedup vs baseline: 1.5563x; 1.5563x over previous
//
#include <hip/hip_runtime.h>
#include <math.h>

#define LN 8      // layers
#define NRBF 256
#define FD 16
#define OUTD 3
#define KC (-0.72134752044f)   // -0.5 * log2(e)

typedef __attribute__((ext_vector_type(8))) short short8;   // 8 x bf16
typedef __attribute__((ext_vector_type(4))) float floatx4;

__device__ __forceinline__ short f2bf(float f) {
    unsigned u = __builtin_bit_cast(unsigned, f);
    u += 0x7fffu + ((u >> 16) & 1u);          // RNE
    return (short)(u >> 16);
}

// Workspace:
//   PKB: short8[(nt*8+j)*64 + lane]  (128 KB)  B-fragments, lane-ordered:
//        n = nt*16+(lane&15), k = (lane>>4)*8+e, m=k>>1 -> {A, -2*A*C}
//   EPI: float4[nt*128 + j*16 + l]   (32 KB)   {KC*t3prefix, w0, w1, w2}, n=nt*16+l

__global__ __launch_bounds__(256) void prep(
    const float* __restrict__ centers, const float* __restrict__ betas,
    const float* __restrict__ W, short* __restrict__ PKB, float* __restrict__ EPI)
{
    __shared__ float ls[LN * 32];
    int blk = blockIdx.x;
    int tid = threadIdx.x;
    if (blk < 32) {
        // ---- PKB: one thread per (j, nt, lane) ----
        int t = blk * 256 + tid;           // 8192 total
        int lane = t & 63;
        int nt   = (t >> 6) & 15;
        int j    = t >> 10;
        int n    = nt * 16 + (lane & 15);
        int kq   = lane >> 4;
        size_t base = ((size_t)(j * NRBF + n)) * FD + kq * 4;
        float4 bq = *(const float4*)(betas + base);
        float4 cq = *(const float4*)(centers + base);
        float a0 = __expf(bq.x), a1 = __expf(bq.y), a2 = __expf(bq.z), a3 = __expf(bq.w);
        short8 v;
        v[0] = f2bf(a0); v[1] = f2bf(-2.0f * a0 * cq.x);
        v[2] = f2bf(a1); v[3] = f2bf(-2.0f * a1 * cq.y);
        v[4] = f2bf(a2); v[5] = f2bf(-2.0f * a2 * cq.z);
        v[6] = f2bf(a3); v[7] = f2bf(-2.0f * a3 * cq.w);
        *((short8*)(PKB + (size_t)((nt * 8 + j) * 64 + lane) * 8)) = v;
    } else {
        // ---- EPI: block handles a 32-wide n slice, all 8 layers ----
        int jj = tid >> 5;                  // 0..7
        int nl = tid & 31;
        int n  = (blk - 32) * 32 + nl;
        const float* bp = betas   + ((size_t)(jj * NRBF + n)) * FD;
        const float* cp = centers + ((size_t)(jj * NRBF + n)) * FD;
        float s = 0.f;
#pragma unroll
        for (int q = 0; q < 4; ++q) {
            float4 bq = *(const float4*)(bp + q * 4);
            float4 cq = *(const float4*)(cp + q * 4);
            s = fmaf(__expf(bq.x) * cq.x, cq.x, s);
            s = fmaf(__expf(bq.y) * cq.y, cq.y, s);
            s = fmaf(__expf(bq.z) * cq.z, cq.z, s);
            s = fmaf(__expf(bq.w) * cq.w, cq.w, s);
        }
        ls[jj * 32 + nl] = s;
        __syncthreads();
        float t3 = 0.f;
        for (int j2 = 0; j2 <= jj; ++j2) t3 += ls[j2 * 32 + nl];
        float4 e;
        e.x = KC * t3;
        e.y = W[0 * (LN * NRBF) + jj * NRBF + n];
        e.z = W[1 * (LN * NRBF) + jj * NRBF + n];
        e.w = W[2 * (LN * NRBF) + jj * NRBF + n];
        int nt = n >> 4, l = n & 15;
        ((float4*)EPI)[nt * 128 + jj * 16 + l] = e;
    }
}

// One BLOCK = one 16-sample tile; 4 waves, wave w handles nt = w*4..w*4+3.
// Per nt: ALL 16 loads (8 bfrag + 8 epi) preloaded into static-index locals
// BEFORE the MFMA/exp chain -> one pipelined latency per nt, not 8 serial.
// launch_bounds(256,4) gives the allocator 128 regs to hold the preload.
__global__ __launch_bounds__(256, 4) void rbf_mfma(
    const float* __restrict__ feats, const short* __restrict__ PKB,
    const float* __restrict__ EPI, const float* __restrict__ bias,
    float* __restrict__ out, int B)
{
    __shared__ float red[4][48];

    int tid  = threadIdx.x;
    int lane = tid & 63;
    int w    = tid >> 6;
    int b0   = blockIdx.x * 16;
    int m    = lane & 15;
    int kq   = lane >> 4;

    // A-fragments: lane holds sample b0+m, k-range kq*8.. of each layer
    int brow = b0 + m; if (brow >= B) brow = B - 1;
    const float* xrow = feats + (size_t)brow * (LN * FD) + kq * 4;
    short8 afrag[LN];
#pragma unroll
    for (int j = 0; j < LN; ++j) {
        float4 x = *((const float4*)(xrow + j * FD));
        short8 f;
        f[0] = f2bf(x.x * x.x); f[1] = f2bf(x.x);
        f[2] = f2bf(x.y * x.y); f[3] = f2bf(x.y);
        f[4] = f2bf(x.z * x.z); f[5] = f2bf(x.z);
        f[6] = f2bf(x.w * x.w); f[7] = f2bf(x.w);
        afrag[j] = f;
    }

    float oacc[12];
#pragma unroll
    for (int i = 0; i < 12; ++i) oacc[i] = 0.f;

#pragma unroll 1
    for (int g = 0; g < 4; ++g) {
        int nt = w * 4 + g;
        const short8* pb = (const short8*)PKB + (size_t)(nt * 8) * 64 + lane;  // j-stride 64
        const float4* ep = (const float4*)EPI + (size_t)nt * 128 + m;          // j-stride 16

        // ---- static-index preload: 16 independent loads issue back-to-back ----
        short8 bf[LN];
        float4 ev[LN];
#pragma unroll
        for (int j = 0; j < LN; ++j) bf[j] = pb[j * 64];
#pragma unroll
        for (int j = 0; j < LN; ++j) ev[j] = ep[j * 16];

        floatx4 acc = {0.f, 0.f, 0.f, 0.f};
#pragma unroll
        for (int j = 0; j < LN; ++j) {
            acc = __builtin_amdgcn_mfma_f32_16x16x32_bf16(afrag[j], bf[j], acc, 0, 0, 0);
#pragma unroll
            for (int r = 0; r < 4; ++r) {
                float rv = __builtin_amdgcn_exp2f(fmaf(acc[r], KC, ev[j].x));
                oacc[r * 3 + 0] = fmaf(rv, ev[j].y, oacc[r * 3 + 0]);
                oacc[r * 3 + 1] = fmaf(rv, ev[j].z, oacc[r * 3 + 1]);
                oacc[r * 3 + 2] = fmaf(rv, ev[j].w, oacc[r * 3 + 2]);
            }
        }
    }

    // intra-wave reduce over the 16 n-lanes (xor 1,2,4,8 stay within kq group)
#pragma unroll
    for (int i = 0; i < 12; ++i) {
        oacc[i] += __shfl_xor(oacc[i], 1);
        oacc[i] += __shfl_xor(oacc[i], 2);
        oacc[i] += __shfl_xor(oacc[i], 4);
        oacc[i] += __shfl_xor(oacc[i], 8);
    }

    if (m < OUTD) {
#pragma unroll
        for (int r = 0; r < 4; ++r)
            red[w][kq * 12 + r * 3 + m] = oacc[r * 3 + m];
    }
    __syncthreads();

    if (tid < 48) {
        int o = tid % 3;
        int idx = b0 * 3 + tid;
        if (idx < B * 3) {
            float s = red[0][tid] + red[1][tid] + red[2][tid] + red[3][tid] + bias[o];
            out[idx] = s;                    // contiguous 192 B per block
        }
    }
}

extern "C" void kernel_launch(void* const* d_in, const int* in_sizes, int n_in,
                              void* d_out, int out_size, void* d_ws, size_t ws_size,
                              hipStream_t stream) {
    // inputs: 0=x (UNUSED by reference), 1=feats, 2=centers, 3=betas, 4=W, 5=b
    const float* feats   = (const float*)d_in[1];
    const float* centers = (const float*)d_in[2];
    const float* betas   = (const float*)d_in[3];
    const float* W       = (const float*)d_in[4];
    const float* bias    = (const float*)d_in[5];
    float* out = (float*)d_out;
    int B = in_sizes[1] / (LN * FD);

    short* PKB = (short*)d_ws;                       // 65536 shorts = 128 KB
    float* EPI = (float*)((char*)d_ws + 65536 * 2);  // 8192 floats = 32 KB

    prep<<<40, 256, 0, stream>>>(centers, betas, W, PKB, EPI);

    int tiles = (B + 15) / 16;
    rbf_mfma<<<tiles, 256, 0, stream>>>(feats, PKB, EPI, bias, out, B);
}